// Round 6
// baseline (172.506 us; speedup 1.0000x reference)
//
#include <hip/hip_runtime.h>
#include <hip/hip_bf16.h>

// FeatureAlign deformable 3x3 conv, G=4, PAD=1.
// R14 = R11 work geometry (512 blk x 512 thr, N=64, 16B gathers) + pipeline
// de-serialization. R13 lesson: grid=512 caps residency at 2 blocks/CU, and
// launch_bounds(512,6) caused spills (VGPR 40, WRITE +21MB scratch). Here:
//  (1) sB quad-buffered, commit runs 2 gk ahead, issue 3 ahead ->
//      barrier every 2 gk (18 instead of 36). All RAW/WAR distances >= 2.
//  (2) barrier is lgkm-only (ds_writes drained; private global gathers stay
//      in flight across it = counted-vmcnt behavior, T4).
//  (3) s_setprio(1) around the MFMA cluster (T5; 2 independent blocks/CU).
//  (4) launch_bounds back to (512,4); two c4/amv register sets with static
//      parity via x2-unrolled loop (rule #20: no runtime-indexed reg arrays).
// Keeps R13's 12B meta packing (correct, bank-conflict-free). fa_prep as R11.

#define Bn   8
#define CIN  256
#define COUT 256
#define Hn   64
#define Wn   64
#define Gn   4
#define Kn   9
#define CPG  64
#define GK   36

typedef float    f32x4 __attribute__((ext_vector_type(4)));
typedef _Float16 f16x2 __attribute__((ext_vector_type(2)));
typedef _Float16 f16x8 __attribute__((ext_vector_type(8)));

// ---------------------------------------------------------------------------
// Fused prep (unchanged from R11).
// ---------------------------------------------------------------------------
#define SWPAD 1156
#define HWT   32
__global__ void fa_prep(const float* __restrict__ x, const float* __restrict__ w,
                        _Float16* __restrict__ xt, _Float16* __restrict__ wfrag) {
    const int bid = blockIdx.x, t = threadIdx.x;
    __shared__ __align__(16) _Float16 spool[16 * SWPAD];   // 36,992 B
    if (bid < 1024) {
        _Float16* sT = spool;                              // 32*256 elems
        const int b = bid >> 7, tile = bid & 127;
        const int hw0 = tile * HWT;
        const int s = t >> 3, hwq = t & 7;
#pragma unroll
        for (int it = 0; it < 8; it++) {
            int c = it * 32 + s;
            float4 v = *(const float4*)(x + (((size_t)(b * CIN + c)) << 12) + hw0 + hwq * 4);
            const float* vf = (const float*)&v;
#pragma unroll
            for (int j = 0; j < 4; j++) {
                int hw = hwq * 4 + j;
                sT[hw * 256 + (c ^ (hwq << 3))] = (_Float16)vf[j];
            }
        }
        __syncthreads();
        const int cg = t & 31, hwr = t >> 5;
#pragma unroll
        for (int it = 0; it < 4; it++) {
            int hw = it * 8 + hwr;
            int q = hw >> 2;
            f16x8 v = *(const f16x8*)&sT[hw * 256 + ((cg ^ q) << 3)];
            *(f16x8*)&xt[(((size_t)b << 12) + hw0 + hw) * 256 + cg * 8] = v;
        }
    } else {
        _Float16* sw = spool;
        const int mt = (bid - 1024) >> 1, gh = (bid - 1024) & 1;
        const int o0 = mt * 16, g0 = gh * 2;
        const int r = t >> 4, tr = t & 15;
        const float* wp = w + (size_t)(o0 + r) * (CIN * Kn) + g0 * (CPG * Kn);
#pragma unroll
        for (int it = 0; it < 18; it++) {
            int off = it * 64 + tr * 4;
            float4 v = *(const float4*)(wp + off);
            _Float16* d = &sw[r * SWPAD + off];
            d[0] = (_Float16)v.x; d[1] = (_Float16)v.y;
            d[2] = (_Float16)v.z; d[3] = (_Float16)v.w;
        }
        __syncthreads();
#pragma unroll
        for (int it = 0; it < 9; it++) {
            int chunk = it * 256 + t;
            int lane = chunk & 63, ks = (chunk >> 6) & 1, gkl = chunk >> 7;
            int gl = gkl / Kn, k = gkl - gl * Kn;
            int gk = g0 * Kn + gkl;
            int ol = lane & 15;
            int cbase = ks * 32 + (lane >> 4) * 8;
            f16x8 v;
#pragma unroll
            for (int j = 0; j < 8; j++)
                v[j] = sw[ol * SWPAD + (gl * CPG + cbase + j) * Kn + k];
            *(f16x8*)&wfrag[(((size_t)gk * 16 + mt) * 2 + ks) * 512 + lane * 8] = v;
        }
    }
}

// ---------------------------------------------------------------------------
// Main: 512 blocks x 512 threads. Block = bp*128 + h*2 + wh.
// N = 64 (2 b x 32 w); M = 256 over 8 waves (32 o-rows each). K = 36*64.
// ---------------------------------------------------------------------------
__global__ __launch_bounds__(512, 4)
void fa_main(const _Float16* __restrict__ xt, const float* __restrict__ shp,
             const float* __restrict__ w_off, const _Float16* __restrict__ wfrag,
             float* __restrict__ out) {
    const int blk = blockIdx.x;
    const int bp = blk >> 7, h = (blk >> 1) & 63, wh = blk & 1;
    const int w0 = wh * 32;
    const int t = threadIdx.x;
    const int wid = t >> 6, lane = t & 63;
    const int col = lane & 15, quad = lane >> 4;
    const int cg = t & 7, nl = (t >> 3) & 63;

    __shared__ int  s_meta_a[GK * 64];                    // 9216 B
    __shared__ __align__(8) int2 s_meta_w[GK * 64];       // 18432 B
    __shared__ __align__(16) _Float16 sB[4][64 * 64];     // 32768 B
    __shared__ float s_shp[2 * 4 * 32];                   // 1024 B
    __shared__ float s_woff[GK * 8];                      // 1152 B
    // total 62,592 B -> 2 blocks/CU

    // ---- stage shp slice (2 b x 4 c x 32 w at row h) + ALL 288 w_off ----
    if (t < 256) {
        int bb = t >> 7, c = (t >> 5) & 3, wl = t & 31;
        s_shp[t] = shp[(((bp * 2 + bb) * 4 + c) << 12) + h * Wn + w0 + wl];
    }
    for (int u = t; u < GK * 8; u += 512) s_woff[u] = w_off[u];
    __syncthreads();

    // ---- meta: 12B (int addr+flags, int2 f16x2 weights) per (gk, n) ----
    for (int i = t; i < GK * 64; i += 512) {
        int gk = i >> 6, n = i & 63;
        int bb = n >> 5, wl = n & 31;
        int g = gk / Kn, k = gk - g * Kn;
        int ky = k / 3, kx = k - ky * 3;
        float dy = 0.f, dx = 0.f;
#pragma unroll
        for (int c = 0; c < 4; c++) {
            float sv = s_shp[(bb * 4 + c) * 32 + wl];
            dy = fmaf(s_woff[gk * 8 + c],     sv, dy);
            dx = fmaf(s_woff[gk * 8 + 4 + c], sv, dx);
        }
        float py = (float)(h + ky - 1) + dy;
        float px = (float)(w0 + wl + kx - 1) + dx;
        float y0 = floorf(py), x0 = floorf(px);
        float fy = py - y0, fx = px - x0;
        int iy = (int)y0, ix = (int)x0;
        bool y0v = (unsigned)iy       < (unsigned)Hn;
        bool y1v = (unsigned)(iy + 1) < (unsigned)Hn;
        bool x0v = (unsigned)ix       < (unsigned)Wn;
        bool x1v = (unsigned)(ix + 1) < (unsigned)Wn;
        int yc0 = min(max(iy, 0), Hn - 1), yc1 = min(max(iy + 1, 0), Hn - 1);
        int xc0 = min(max(ix, 0), Wn - 1), xc1 = min(max(ix + 1, 0), Wn - 1);
        int l00 = yc0 * Wn + xc0;
        int dx1 = xc1 - xc0, dy1 = yc1 - yc0;             // in {0,1}
        float wy1 = fy, wy0 = 1.f - fy, wx1 = fx, wx0 = 1.f - fx;
        float w00 = (y0v && x0v) ? wy0 * wx0 : 0.f;
        float w01 = (y0v && x1v) ? wy0 * wx1 : 0.f;
        float w10 = (y1v && x0v) ? wy1 * wx0 : 0.f;
        float w11 = (y1v && x1v) ? wy1 * wx1 : 0.f;
        f16x2 p0, p1;
        p0.x = (_Float16)w00; p0.y = (_Float16)w01;
        p1.x = (_Float16)w10; p1.y = (_Float16)w11;
        s_meta_a[i] = l00 | (dx1 << 12) | (dy1 << 13);
        s_meta_w[i] = make_int2(__builtin_bit_cast(int, p0),
                                __builtin_bit_cast(int, p1));
    }

    // two register sets: A holds even-gk gathers, B holds odd-gk gathers
    f16x8 c4A[4], c4B[4];
    int2  amvA, amvB;
    const unsigned nBase = ((unsigned)(bp * 2 + (nl >> 5)) << 20) + (unsigned)cg * 8u;

    auto issue = [&](int gk, f16x8 (&c4)[4], int2& amv) {
        int aw = s_meta_a[gk * 64 + nl];
        amv = s_meta_w[gk * 64 + nl];
        unsigned g = (unsigned)gk / (unsigned)Kn;
        const _Float16* p = xt + nBase + g * 64u;
        unsigned a00 = ((unsigned)aw & 0xFFFu) << 8;       // l00 * 256
        unsigned dxo = ((unsigned)aw & 0x1000u) >> 4;      // dx1 * 256
        unsigned dyo = ((unsigned)aw & 0x2000u) << 1;      // dy1 * 64*256
        c4[0] = *(const f16x8*)(p + a00);
        c4[1] = *(const f16x8*)(p + a00 + dxo);
        c4[2] = *(const f16x8*)(p + a00 + dyo);
        c4[3] = *(const f16x8*)(p + a00 + (dxo + dyo));
    };
    auto commit = [&](int buf, f16x8 (&c4)[4], int2& amv) {
        f16x2 wv0 = __builtin_bit_cast(f16x2, amv.x);     // {w00, w01}
        f16x2 wv1 = __builtin_bit_cast(f16x2, amv.y);     // {w10, w11}
        f16x2 w00 = __builtin_shufflevector(wv0, wv0, 0, 0);
        f16x2 w01 = __builtin_shufflevector(wv0, wv0, 1, 1);
        f16x2 w10 = __builtin_shufflevector(wv1, wv1, 0, 0);
        f16x2 w11 = __builtin_shufflevector(wv1, wv1, 1, 1);
        const f16x2* a0p = (const f16x2*)&c4[0];
        const f16x2* a1p = (const f16x2*)&c4[1];
        const f16x2* a2p = (const f16x2*)&c4[2];
        const f16x2* a3p = (const f16x2*)&c4[3];
        f16x8 r;
        f16x2* rp = (f16x2*)&r;
#pragma unroll
        for (int p = 0; p < 4; p++) {
            f16x2 rv = w00 * a0p[p] + w01 * a1p[p]
                     + w10 * a2p[p] + w11 * a3p[p];        // v_pk_fma_f16
            rp[p] = rv;
        }
        *(f16x8*)&sB[buf][(nl * 8 + (cg ^ (nl & 7))) * 8] = r;
    };

    f32x4 acc[2][4];
#pragma unroll
    for (int mt = 0; mt < 2; mt++)
#pragma unroll
        for (int nt = 0; nt < 4; nt++) acc[mt][nt] = (f32x4){0.f, 0.f, 0.f, 0.f};

    __syncthreads();            // meta visible

    // prologue: sB[0],sB[1] filled; c4A<-gk2 in flight
    issue(0, c4A, amvA);
    issue(1, c4B, amvB);
    commit(0, c4A, amvA);
    issue(2, c4A, amvA);
    commit(1, c4B, amvB);
    __syncthreads();

    // main loop: pairs of gk; barrier (lgkm-only) once per pair.
    // iter j: MFMA(sB[j&3]); commit(j+2)->sB[(j+2)&3]; issue(j+3).
    // even j: commit reads c4A, issue writes c4B; odd j: swapped.
    for (int jj = 0; jj < GK; jj += 2) {
        // ---------------- even body: j = jj ----------------
        {
            const int j = jj;
            const _Float16* wbase = wfrag + (((size_t)j * 16 + wid * 2) * 2) * 512;
            f16x8 af[2][2];
#pragma unroll
            for (int ks = 0; ks < 2; ks++)
#pragma unroll
                for (int mt = 0; mt < 2; mt++)
                    af[ks][mt] = *(const f16x8*)(wbase + ((size_t)(mt * 2 + ks) * 64 + lane) * 8);
            const _Float16* sBj = sB[j & 3];
            f16x8 bfv[2][4];
#pragma unroll
            for (int ks = 0; ks < 2; ks++)
#pragma unroll
                for (int nt = 0; nt < 4; nt++) {
                    int n = nt * 16 + col;
                    int cq8 = ks * 4 + quad;
                    bfv[ks][nt] = *(const f16x8*)&sBj[(n * 8 + (cq8 ^ (n & 7))) * 8];
                }
            if (j + 2 < GK) commit((j + 2) & 3, c4A, amvA);
            if (j + 3 < GK) issue(j + 3, c4B, amvB);
            __builtin_amdgcn_s_setprio(1);
#pragma unroll
            for (int ks = 0; ks < 2; ks++)
#pragma unroll
                for (int mt = 0; mt < 2; mt++)
#pragma unroll
                    for (int nt = 0; nt < 4; nt++)
                        acc[mt][nt] = __builtin_amdgcn_mfma_f32_16x16x32_f16(
                            af[ks][mt], bfv[ks][nt], acc[mt][nt], 0, 0, 0);
            __builtin_amdgcn_s_setprio(0);
        }
        // ---------------- odd body: j = jj + 1 ----------------
        {
            const int j = jj + 1;
            const _Float16* wbase = wfrag + (((size_t)j * 16 + wid * 2) * 2) * 512;
            f16x8 af[2][2];
#pragma unroll
            for (int ks = 0; ks < 2; ks++)
#pragma unroll
                for (int mt = 0; mt < 2; mt++)
                    af[ks][mt] = *(const f16x8*)(wbase + ((size_t)(mt * 2 + ks) * 64 + lane) * 8);
            const _Float16* sBj = sB[j & 3];
            f16x8 bfv[2][4];
#pragma unroll
            for (int ks = 0; ks < 2; ks++)
#pragma unroll
                for (int nt = 0; nt < 4; nt++) {
                    int n = nt * 16 + col;
                    int cq8 = ks * 4 + quad;
                    bfv[ks][nt] = *(const f16x8*)&sBj[(n * 8 + (cq8 ^ (n & 7))) * 8];
                }
            if (j + 2 < GK) commit((j + 2) & 3, c4B, amvB);
            if (j + 3 < GK) issue(j + 3, c4A, amvA);
            __builtin_amdgcn_s_setprio(1);
#pragma unroll
            for (int ks = 0; ks < 2; ks++)
#pragma unroll
                for (int mt = 0; mt < 2; mt++)
#pragma unroll
                    for (int nt = 0; nt < 4; nt++)
                        acc[mt][nt] = __builtin_amdgcn_mfma_f32_16x16x32_f16(
                            af[ks][mt], bfv[ks][nt], acc[mt][nt], 0, 0, 0);
            __builtin_amdgcn_s_setprio(0);
            // lgkm-only barrier: ds_writes of this pair visible; private
            // global gathers (c4) stay in flight across the barrier (T4).
            asm volatile("s_waitcnt lgkmcnt(0)" ::: "memory");
            __builtin_amdgcn_s_barrier();
        }
    }

    // ---- epilogue: o = wid*32 + mt*16 + quad*4 + r ; n = nt*16 + col ----
#pragma unroll
    for (int mt = 0; mt < 2; mt++)
#pragma unroll
        for (int r = 0; r < 4; r++) {
            int o = wid * 32 + mt * 16 + quad * 4 + r;
#pragma unroll
            for (int nt = 0; nt < 4; nt++) {
                int n = nt * 16 + col;
                int b = bp * 2 + (n >> 5);
                int w = w0 + (n & 31);
                out[(((size_t)(b * COUT + o)) << 12) + h * Wn + w] =
                    fmaxf(acc[mt][nt][r], 0.f);
            }
        }
}

// ---------------------------------------------------------------------------
extern "C" void kernel_launch(void* const* d_in, const int* in_sizes, int n_in,
                              void* d_out, int out_size, void* d_ws, size_t ws_size,
                              hipStream_t stream) {
    const float* x     = (const float*)d_in[0];
    const float* shp   = (const float*)d_in[1];
    const float* w_off = (const float*)d_in[2];
    const float* w_def = (const float*)d_in[3];
    float* out = (float*)d_out;
    _Float16* wfrag = (_Float16*)d_ws;                       // 1.18 MB
    _Float16* xt    = (_Float16*)((char*)d_ws + (2u << 20)); // 16.8 MB

    fa_prep<<<1024 + 32, 256, 0, stream>>>(x, w_def, xt, wfrag);
    fa_main<<<512, 512, 0, stream>>>(xt, shp, w_off, wfrag, out);
}

// Round 7
// 140.518 us; speedup vs baseline: 1.2277x; 1.2277x over previous
//
#include <hip/hip_runtime.h>
#include <hip/hip_bf16.h>

// FeatureAlign deformable 3x3 conv, G=4, PAD=1.
// R15 = R11 (best: 58.6us fa_main, VGPR 52, no spills) + three zero-register
// changes; R13/R14 both died to allocator spills from added register state,
// so this round touches ONLY things that cost no VGPRs:
//  (1) loop barrier = s_waitcnt lgkmcnt(0) + s_barrier (not __syncthreads):
//      sB is the only cross-wave data; private c4/af global loads stay in
//      flight across the barrier instead of being drained by vmcnt(0) every
//      iter (~300-500 exposed cycles). Compiler still counted-waits each use.
//  (2) XCD-aware block remap: xcd=blk&7 -> bp=xcd>>1, so each XCD's L2 only
//      serves ONE batch-pair's gather slice (~1MB/gk-group, fits 4MB L2);
//      default round-robin thrashed all 4 pairs through every XCD -> L3.
//  (3) R13's 12B meta packing (correct, bank-conflict-free, LDS 46.2KB).
// Work geometry, register structure, commit/issue/MFMA order = R11 verbatim.

#define Bn   8
#define CIN  256
#define COUT 256
#define Hn   64
#define Wn   64
#define Gn   4
#define Kn   9
#define CPG  64
#define GK   36

typedef float    f32x4 __attribute__((ext_vector_type(4)));
typedef _Float16 f16x2 __attribute__((ext_vector_type(2)));
typedef _Float16 f16x8 __attribute__((ext_vector_type(8)));

// ---------------------------------------------------------------------------
// Fused prep (unchanged from R11).
//  blocks [0, 1024):        x (b,c,y,x) f32 -> xt (b, y*64+x, c) f16 [NHWC]
//  blocks [1024, 1024+32):  w_deform -> fragment-linear f16 wfrag
// ---------------------------------------------------------------------------
#define SWPAD 1156
#define HWT   32
__global__ void fa_prep(const float* __restrict__ x, const float* __restrict__ w,
                        _Float16* __restrict__ xt, _Float16* __restrict__ wfrag) {
    const int bid = blockIdx.x, t = threadIdx.x;
    __shared__ __align__(16) _Float16 spool[16 * SWPAD];   // 36,992 B
    if (bid < 1024) {
        _Float16* sT = spool;                              // 32*256 elems
        const int b = bid >> 7, tile = bid & 127;
        const int hw0 = tile * HWT;
        const int s = t >> 3, hwq = t & 7;
#pragma unroll
        for (int it = 0; it < 8; it++) {
            int c = it * 32 + s;
            float4 v = *(const float4*)(x + (((size_t)(b * CIN + c)) << 12) + hw0 + hwq * 4);
            const float* vf = (const float*)&v;
#pragma unroll
            for (int j = 0; j < 4; j++) {
                int hw = hwq * 4 + j;
                sT[hw * 256 + (c ^ (hwq << 3))] = (_Float16)vf[j];
            }
        }
        __syncthreads();
        const int cg = t & 31, hwr = t >> 5;
#pragma unroll
        for (int it = 0; it < 4; it++) {
            int hw = it * 8 + hwr;
            int q = hw >> 2;
            f16x8 v = *(const f16x8*)&sT[hw * 256 + ((cg ^ q) << 3)];
            *(f16x8*)&xt[(((size_t)b << 12) + hw0 + hw) * 256 + cg * 8] = v;
        }
    } else {
        _Float16* sw = spool;
        const int mt = (bid - 1024) >> 1, gh = (bid - 1024) & 1;
        const int o0 = mt * 16, g0 = gh * 2;
        const int r = t >> 4, tr = t & 15;
        const float* wp = w + (size_t)(o0 + r) * (CIN * Kn) + g0 * (CPG * Kn);
#pragma unroll
        for (int it = 0; it < 18; it++) {
            int off = it * 64 + tr * 4;
            float4 v = *(const float4*)(wp + off);
            _Float16* d = &sw[r * SWPAD + off];
            d[0] = (_Float16)v.x; d[1] = (_Float16)v.y;
            d[2] = (_Float16)v.z; d[3] = (_Float16)v.w;
        }
        __syncthreads();
#pragma unroll
        for (int it = 0; it < 9; it++) {
            int chunk = it * 256 + t;
            int lane = chunk & 63, ks = (chunk >> 6) & 1, gkl = chunk >> 7;
            int gl = gkl / Kn, k = gkl - gl * Kn;
            int gk = g0 * Kn + gkl;
            int ol = lane & 15;
            int cbase = ks * 32 + (lane >> 4) * 8;
            f16x8 v;
#pragma unroll
            for (int j = 0; j < 8; j++)
                v[j] = sw[ol * SWPAD + (gl * CPG + cbase + j) * Kn + k];
            *(f16x8*)&wfrag[(((size_t)gk * 16 + mt) * 2 + ks) * 512 + lane * 8] = v;
        }
    }
}

// ---------------------------------------------------------------------------
// Main: 512 blocks x 512 threads.
// XCD-aware remap (dispatch round-robins blk%8 across XCDs):
//   xcd = blk&7, slot = blk>>3; bp = xcd>>1; h = (slot>>1)*2 + (xcd&1);
//   wh = slot&1.  -> each XCD serves exactly one batch-pair (bijective).
// N = 64 (2 b x 32 w); M = 256 over 8 waves (32 o-rows each). K = 36*64.
// ---------------------------------------------------------------------------
__global__ __launch_bounds__(512, 4)
void fa_main(const _Float16* __restrict__ xt, const float* __restrict__ shp,
             const float* __restrict__ w_off, const _Float16* __restrict__ wfrag,
             float* __restrict__ out) {
    const int blk = blockIdx.x;
    const int xcd = blk & 7, slot = blk >> 3;
    const int bp = xcd >> 1;
    const int h = (slot >> 1) * 2 + (xcd & 1);
    const int wh = slot & 1;
    const int w0 = wh * 32;
    const int t = threadIdx.x;
    const int wid = t >> 6, lane = t & 63;
    const int col = lane & 15, quad = lane >> 4;
    const int cg = t & 7, nl = (t >> 3) & 63;

    __shared__ int  s_meta_a[GK * 64];                    // 9216 B
    __shared__ __align__(8) int2 s_meta_w[GK * 64];       // 18432 B
    __shared__ __align__(16) _Float16 sB[2][64 * 64];     // 16384 B
    __shared__ float s_shp[2 * 4 * 32];                   // 1024 B
    __shared__ float s_woff[GK * 8];                      // 1152 B
    // total 46,208 B

    // ---- stage shp slice (2 b x 4 c x 32 w at row h) + ALL 288 w_off ----
    if (t < 256) {
        int bb = t >> 7, c = (t >> 5) & 3, wl = t & 31;
        s_shp[t] = shp[(((bp * 2 + bb) * 4 + c) << 12) + h * Wn + w0 + wl];
    }
    for (int u = t; u < GK * 8; u += 512) s_woff[u] = w_off[u];
    __syncthreads();

    // ---- meta: 12B (int addr+flags, int2 f16x2 weights) per (gk, n) ----
    for (int i = t; i < GK * 64; i += 512) {
        int gk = i >> 6, n = i & 63;
        int bb = n >> 5, wl = n & 31;
        int g = gk / Kn, k = gk - g * Kn;
        int ky = k / 3, kx = k - ky * 3;
        float dy = 0.f, dx = 0.f;
#pragma unroll
        for (int c = 0; c < 4; c++) {
            float sv = s_shp[(bb * 4 + c) * 32 + wl];
            dy = fmaf(s_woff[gk * 8 + c],     sv, dy);
            dx = fmaf(s_woff[gk * 8 + 4 + c], sv, dx);
        }
        float py = (float)(h + ky - 1) + dy;
        float px = (float)(w0 + wl + kx - 1) + dx;
        float y0 = floorf(py), x0 = floorf(px);
        float fy = py - y0, fx = px - x0;
        int iy = (int)y0, ix = (int)x0;
        bool y0v = (unsigned)iy       < (unsigned)Hn;
        bool y1v = (unsigned)(iy + 1) < (unsigned)Hn;
        bool x0v = (unsigned)ix       < (unsigned)Wn;
        bool x1v = (unsigned)(ix + 1) < (unsigned)Wn;
        int yc0 = min(max(iy, 0), Hn - 1), yc1 = min(max(iy + 1, 0), Hn - 1);
        int xc0 = min(max(ix, 0), Wn - 1), xc1 = min(max(ix + 1, 0), Wn - 1);
        int l00 = yc0 * Wn + xc0;
        int dx1 = xc1 - xc0, dy1 = yc1 - yc0;             // in {0,1}
        float wy1 = fy, wy0 = 1.f - fy, wx1 = fx, wx0 = 1.f - fx;
        float w00 = (y0v && x0v) ? wy0 * wx0 : 0.f;
        float w01 = (y0v && x1v) ? wy0 * wx1 : 0.f;
        float w10 = (y1v && x0v) ? wy1 * wx0 : 0.f;
        float w11 = (y1v && x1v) ? wy1 * wx1 : 0.f;
        f16x2 p0, p1;
        p0.x = (_Float16)w00; p0.y = (_Float16)w01;
        p1.x = (_Float16)w10; p1.y = (_Float16)w11;
        s_meta_a[i] = l00 | (dx1 << 12) | (dy1 << 13);
        s_meta_w[i] = make_int2(__builtin_bit_cast(int, p0),
                                __builtin_bit_cast(int, p1));
    }

    f16x8 c4[4];
    int2  amv;
    const unsigned nBase = ((unsigned)(bp * 2 + (nl >> 5)) << 20) + (unsigned)cg * 8u;

    auto issue = [&](int gk) {
        int aw = s_meta_a[gk * 64 + nl];
        amv = s_meta_w[gk * 64 + nl];
        unsigned g = (unsigned)gk / (unsigned)Kn;
        const _Float16* p = xt + nBase + g * 64u;
        unsigned a00 = ((unsigned)aw & 0xFFFu) << 8;       // l00 * 256
        unsigned dxo = ((unsigned)aw & 0x1000u) >> 4;      // dx1 * 256
        unsigned dyo = ((unsigned)aw & 0x2000u) << 1;      // dy1 * 64*256
        c4[0] = *(const f16x8*)(p + a00);
        c4[1] = *(const f16x8*)(p + a00 + dxo);
        c4[2] = *(const f16x8*)(p + a00 + dyo);
        c4[3] = *(const f16x8*)(p + a00 + (dxo + dyo));
    };
    auto commit = [&](int buf) {
        f16x2 wv0 = __builtin_bit_cast(f16x2, amv.x);     // {w00, w01}
        f16x2 wv1 = __builtin_bit_cast(f16x2, amv.y);     // {w10, w11}
        f16x2 w00 = __builtin_shufflevector(wv0, wv0, 0, 0);
        f16x2 w01 = __builtin_shufflevector(wv0, wv0, 1, 1);
        f16x2 w10 = __builtin_shufflevector(wv1, wv1, 0, 0);
        f16x2 w11 = __builtin_shufflevector(wv1, wv1, 1, 1);
        const f16x2* a0p = (const f16x2*)&c4[0];
        const f16x2* a1p = (const f16x2*)&c4[1];
        const f16x2* a2p = (const f16x2*)&c4[2];
        const f16x2* a3p = (const f16x2*)&c4[3];
        f16x8 r;
        f16x2* rp = (f16x2*)&r;
#pragma unroll
        for (int p = 0; p < 4; p++) {
            f16x2 rv = w00 * a0p[p] + w01 * a1p[p]
                     + w10 * a2p[p] + w11 * a3p[p];        // v_pk_fma_f16
            rp[p] = rv;
        }
        *(f16x8*)&sB[buf][(nl * 8 + (cg ^ (nl & 7))) * 8] = r;
    };

    f32x4 acc[2][4];
#pragma unroll
    for (int mt = 0; mt < 2; mt++)
#pragma unroll
        for (int nt = 0; nt < 4; nt++) acc[mt][nt] = (f32x4){0.f, 0.f, 0.f, 0.f};

    __syncthreads();            // meta visible

    issue(0);
    commit(0);                  // sB[0] = tile 0
    issue(1);                   // corners(1) in regs
    __syncthreads();

    for (int gk = 0; gk < GK; gk++) {
        const int buf = gk & 1;
        // 1) A-frags for THIS gk
        const _Float16* wbase = wfrag + (((size_t)gk * 16 + wid * 2) * 2) * 512;
        f16x8 af[2][2];
#pragma unroll
        for (int ks = 0; ks < 2; ks++)
#pragma unroll
            for (int mt = 0; mt < 2; mt++)
                af[ks][mt] = *(const f16x8*)(wbase + ((size_t)(mt * 2 + ks) * 64 + lane) * 8);
        // 2) B-frags EARLY (sB[buf] written before last barrier)
        f16x8 bfv[2][4];
#pragma unroll
        for (int ks = 0; ks < 2; ks++)
#pragma unroll
            for (int nt = 0; nt < 4; nt++) {
                int n = nt * 16 + col;
                int cq8 = ks * 4 + quad;
                bfv[ks][nt] = *(const f16x8*)&sB[buf][(n * 8 + (cq8 ^ (n & 7))) * 8];
            }
        // 3) interp gk+1 (corners landed last iter) -> other buffer
        if (gk + 1 < GK) commit(buf ^ 1);
        // 4) corner loads for gk+2 (stay in flight across the barrier)
        if (gk + 2 < GK) issue(gk + 2);
        // 5) MFMA
#pragma unroll
        for (int ks = 0; ks < 2; ks++)
#pragma unroll
            for (int mt = 0; mt < 2; mt++)
#pragma unroll
                for (int nt = 0; nt < 4; nt++)
                    acc[mt][nt] = __builtin_amdgcn_mfma_f32_16x16x32_f16(
                        af[ks][mt], bfv[ks][nt], acc[mt][nt], 0, 0, 0);
        // 6) lgkm-only barrier: all ds_writes (commit) and ds_reads (bfv)
        //    of this iter are complete; private global gathers are NOT
        //    drained (the win vs __syncthreads' vmcnt(0)).
        asm volatile("s_waitcnt lgkmcnt(0)" ::: "memory");
        __builtin_amdgcn_s_barrier();
    }

    // ---- epilogue: o = wid*32 + mt*16 + quad*4 + r ; n = nt*16 + col ----
#pragma unroll
    for (int mt = 0; mt < 2; mt++)
#pragma unroll
        for (int r = 0; r < 4; r++) {
            int o = wid * 32 + mt * 16 + quad * 4 + r;
#pragma unroll
            for (int nt = 0; nt < 4; nt++) {
                int n = nt * 16 + col;
                int b = bp * 2 + (n >> 5);
                int w = w0 + (n & 31);
                out[(((size_t)(b * COUT + o)) << 12) + h * Wn + w] =
                    fmaxf(acc[mt][nt][r], 0.f);
            }
        }
}

// ---------------------------------------------------------------------------
extern "C" void kernel_launch(void* const* d_in, const int* in_sizes, int n_in,
                              void* d_out, int out_size, void* d_ws, size_t ws_size,
                              hipStream_t stream) {
    const float* x     = (const float*)d_in[0];
    const float* shp   = (const float*)d_in[1];
    const float* w_off = (const float*)d_in[2];
    const float* w_def = (const float*)d_in[3];
    float* out = (float*)d_out;
    _Float16* wfrag = (_Float16*)d_ws;                       // 1.18 MB
    _Float16* xt    = (_Float16*)((char*)d_ws + (2u << 20)); // 16.8 MB

    fa_prep<<<1024 + 32, 256, 0, stream>>>(x, w_def, xt, wfrag);
    fa_main<<<512, 512, 0, stream>>>(xt, shp, w_off, wfrag, out);
}

// Round 8
// 138.274 us; speedup vs baseline: 1.2476x; 1.0162x over previous
//
#include <hip/hip_runtime.h>
#include <hip/hip_bf16.h>

// FeatureAlign deformable 3x3 conv, G=4, PAD=1.
// R16 = R15 + BK=128: two gk per barrier (18 barriers instead of 36).
// R14 tried this but spilled (115MB scratch) because its lambdas took the
// corner arrays as by-reference ARRAY PARAMETERS (address taken -> scratch).
// Here the two corner sets c4a/c4b are macro-expanded with static names.
// sB = [2 pair-buffers][2 sub-tiles][64x64] = 32KB; LDS 62.6KB, 2 blocks/CU.
// Pipeline: commit distance 2 gk, issue distance 4 gk. RAW/WAR all cross
// exactly one barrier. Numerics identical to R15 (same gk order per acc).
// Keeps: XCD-aware remap, lgkm-only barrier (private global loads stay in
// flight), 12B meta packing, f16 interp pipeline, fa_prep unchanged.

#define Bn   8
#define CIN  256
#define COUT 256
#define Hn   64
#define Wn   64
#define Gn   4
#define Kn   9
#define CPG  64
#define GK   36

typedef float    f32x4 __attribute__((ext_vector_type(4)));
typedef _Float16 f16x2 __attribute__((ext_vector_type(2)));
typedef _Float16 f16x8 __attribute__((ext_vector_type(8)));

// ---------------------------------------------------------------------------
// Fused prep (unchanged from R11/R15).
//  blocks [0, 1024):        x (b,c,y,x) f32 -> xt (b, y*64+x, c) f16 [NHWC]
//  blocks [1024, 1024+32):  w_deform -> fragment-linear f16 wfrag
// ---------------------------------------------------------------------------
#define SWPAD 1156
#define HWT   32
__global__ void fa_prep(const float* __restrict__ x, const float* __restrict__ w,
                        _Float16* __restrict__ xt, _Float16* __restrict__ wfrag) {
    const int bid = blockIdx.x, t = threadIdx.x;
    __shared__ __align__(16) _Float16 spool[16 * SWPAD];   // 36,992 B
    if (bid < 1024) {
        _Float16* sT = spool;                              // 32*256 elems
        const int b = bid >> 7, tile = bid & 127;
        const int hw0 = tile * HWT;
        const int s = t >> 3, hwq = t & 7;
#pragma unroll
        for (int it = 0; it < 8; it++) {
            int c = it * 32 + s;
            float4 v = *(const float4*)(x + (((size_t)(b * CIN + c)) << 12) + hw0 + hwq * 4);
            const float* vf = (const float*)&v;
#pragma unroll
            for (int j = 0; j < 4; j++) {
                int hw = hwq * 4 + j;
                sT[hw * 256 + (c ^ (hwq << 3))] = (_Float16)vf[j];
            }
        }
        __syncthreads();
        const int cg = t & 31, hwr = t >> 5;
#pragma unroll
        for (int it = 0; it < 4; it++) {
            int hw = it * 8 + hwr;
            int q = hw >> 2;
            f16x8 v = *(const f16x8*)&sT[hw * 256 + ((cg ^ q) << 3)];
            *(f16x8*)&xt[(((size_t)b << 12) + hw0 + hw) * 256 + cg * 8] = v;
        }
    } else {
        _Float16* sw = spool;
        const int mt = (bid - 1024) >> 1, gh = (bid - 1024) & 1;
        const int o0 = mt * 16, g0 = gh * 2;
        const int r = t >> 4, tr = t & 15;
        const float* wp = w + (size_t)(o0 + r) * (CIN * Kn) + g0 * (CPG * Kn);
#pragma unroll
        for (int it = 0; it < 18; it++) {
            int off = it * 64 + tr * 4;
            float4 v = *(const float4*)(wp + off);
            _Float16* d = &sw[r * SWPAD + off];
            d[0] = (_Float16)v.x; d[1] = (_Float16)v.y;
            d[2] = (_Float16)v.z; d[3] = (_Float16)v.w;
        }
        __syncthreads();
#pragma unroll
        for (int it = 0; it < 9; it++) {
            int chunk = it * 256 + t;
            int lane = chunk & 63, ks = (chunk >> 6) & 1, gkl = chunk >> 7;
            int gl = gkl / Kn, k = gkl - gl * Kn;
            int gk = g0 * Kn + gkl;
            int ol = lane & 15;
            int cbase = ks * 32 + (lane >> 4) * 8;
            f16x8 v;
#pragma unroll
            for (int j = 0; j < 8; j++)
                v[j] = sw[ol * SWPAD + (gl * CPG + cbase + j) * Kn + k];
            *(f16x8*)&wfrag[(((size_t)gk * 16 + mt) * 2 + ks) * 512 + lane * 8] = v;
        }
    }
}

// ---------------------------------------------------------------------------
// Main: 512 blocks x 512 threads. XCD-aware remap (blk%8 -> XCD):
//   xcd = blk&7, slot = blk>>3; bp = xcd>>1; h = (slot>>1)*2 + (xcd&1);
//   wh = slot&1. Each XCD serves one batch-pair (bijective).
// N = 64 (2 b x 32 w); M = 256 over 8 waves. K = 36*64, BK = 128 (gk pairs).
// ---------------------------------------------------------------------------

// corner gather: loads 4x16B into C4[0..3], weights into AMV
#define ISSUE(C4, AMV, gk) do {                                              \
    int aw_ = s_meta_a[(gk) * 64 + nl];                                      \
    AMV = s_meta_w[(gk) * 64 + nl];                                          \
    unsigned g_ = (unsigned)(gk) / (unsigned)Kn;                             \
    const _Float16* p_ = xt + nBase + g_ * 64u;                              \
    unsigned a00_ = ((unsigned)aw_ & 0xFFFu) << 8;                           \
    unsigned dxo_ = ((unsigned)aw_ & 0x1000u) >> 4;                          \
    unsigned dyo_ = ((unsigned)aw_ & 0x2000u) << 1;                          \
    C4[0] = *(const f16x8*)(p_ + a00_);                                      \
    C4[1] = *(const f16x8*)(p_ + a00_ + dxo_);                               \
    C4[2] = *(const f16x8*)(p_ + a00_ + dyo_);                               \
    C4[3] = *(const f16x8*)(p_ + a00_ + (dxo_ + dyo_));                      \
} while (0)

// packed-f16 bilinear interp of C4 -> sB[BUF][SUB]
#define COMMIT(C4, AMV, BUF, SUB) do {                                       \
    f16x2 wv0_ = __builtin_bit_cast(f16x2, AMV.x);                           \
    f16x2 wv1_ = __builtin_bit_cast(f16x2, AMV.y);                           \
    f16x2 w00_ = __builtin_shufflevector(wv0_, wv0_, 0, 0);                  \
    f16x2 w01_ = __builtin_shufflevector(wv0_, wv0_, 1, 1);                  \
    f16x2 w10_ = __builtin_shufflevector(wv1_, wv1_, 0, 0);                  \
    f16x2 w11_ = __builtin_shufflevector(wv1_, wv1_, 1, 1);                  \
    const f16x2* a0p_ = (const f16x2*)&C4[0];                                \
    const f16x2* a1p_ = (const f16x2*)&C4[1];                                \
    const f16x2* a2p_ = (const f16x2*)&C4[2];                                \
    const f16x2* a3p_ = (const f16x2*)&C4[3];                                \
    f16x8 r_;                                                                \
    f16x2* rp_ = (f16x2*)&r_;                                                \
    _Pragma("unroll")                                                        \
    for (int p = 0; p < 4; p++)                                              \
        rp_[p] = w00_ * a0p_[p] + w01_ * a1p_[p]                             \
               + w10_ * a2p_[p] + w11_ * a3p_[p];                            \
    *(f16x8*)&sB[BUF][SUB][(nl * 8 + (cg ^ (nl & 7))) * 8] = r_;             \
} while (0)

// one gk worth of af/bfv loads + MFMA; COMMIT/ISSUE spliced between loads
// and MFMA so global latency hides under the matrix work.
#define HALF(GKI, RB, SUB, PIPE) do {                                        \
    const _Float16* wbase_ = wfrag + (((size_t)(GKI) * 16 + wid * 2) * 2) * 512; \
    f16x8 af_[2][2];                                                         \
    _Pragma("unroll")                                                        \
    for (int ks = 0; ks < 2; ks++)                                           \
        _Pragma("unroll")                                                    \
        for (int mt = 0; mt < 2; mt++)                                       \
            af_[ks][mt] = *(const f16x8*)(wbase_ + ((size_t)(mt * 2 + ks) * 64 + lane) * 8); \
    f16x8 bfv_[2][4];                                                        \
    _Pragma("unroll")                                                        \
    for (int ks = 0; ks < 2; ks++)                                           \
        _Pragma("unroll")                                                    \
        for (int nt = 0; nt < 4; nt++) {                                     \
            int n = nt * 16 + col;                                           \
            int cq8 = ks * 4 + quad;                                         \
            bfv_[ks][nt] = *(const f16x8*)&sB[RB][SUB][(n * 8 + (cq8 ^ (n & 7))) * 8]; \
        }                                                                    \
    PIPE                                                                     \
    _Pragma("unroll")                                                        \
    for (int ks = 0; ks < 2; ks++)                                           \
        _Pragma("unroll")                                                    \
        for (int mt = 0; mt < 2; mt++)                                       \
            _Pragma("unroll")                                                 \
            for (int nt = 0; nt < 4; nt++)                                   \
                acc[mt][nt] = __builtin_amdgcn_mfma_f32_16x16x32_f16(        \
                    af_[ks][mt], bfv_[ks][nt], acc[mt][nt], 0, 0, 0);        \
} while (0)

__global__ __launch_bounds__(512, 4)
void fa_main(const _Float16* __restrict__ xt, const float* __restrict__ shp,
             const float* __restrict__ w_off, const _Float16* __restrict__ wfrag,
             float* __restrict__ out) {
    const int blk = blockIdx.x;
    const int xcd = blk & 7, slot = blk >> 3;
    const int bp = xcd >> 1;
    const int h = (slot >> 1) * 2 + (xcd & 1);
    const int wh = slot & 1;
    const int w0 = wh * 32;
    const int t = threadIdx.x;
    const int wid = t >> 6, lane = t & 63;
    const int col = lane & 15, quad = lane >> 4;
    const int cg = t & 7, nl = (t >> 3) & 63;

    __shared__ int  s_meta_a[GK * 64];                    // 9216 B
    __shared__ __align__(8) int2 s_meta_w[GK * 64];       // 18432 B
    __shared__ __align__(16) _Float16 sB[2][2][64 * 64];  // 32768 B
    __shared__ float s_shp[2 * 4 * 32];                   // 1024 B
    __shared__ float s_woff[GK * 8];                      // 1152 B
    // total 62,592 B -> 2 blocks/CU

    // ---- stage shp slice (2 b x 4 c x 32 w at row h) + ALL 288 w_off ----
    if (t < 256) {
        int bb = t >> 7, c = (t >> 5) & 3, wl = t & 31;
        s_shp[t] = shp[(((bp * 2 + bb) * 4 + c) << 12) + h * Wn + w0 + wl];
    }
    for (int u = t; u < GK * 8; u += 512) s_woff[u] = w_off[u];
    __syncthreads();

    // ---- meta: 12B (int addr+flags, int2 f16x2 weights) per (gk, n) ----
    for (int i = t; i < GK * 64; i += 512) {
        int gk = i >> 6, n = i & 63;
        int bb = n >> 5, wl = n & 31;
        int g = gk / Kn, k = gk - g * Kn;
        int ky = k / 3, kx = k - ky * 3;
        float dy = 0.f, dx = 0.f;
#pragma unroll
        for (int c = 0; c < 4; c++) {
            float sv = s_shp[(bb * 4 + c) * 32 + wl];
            dy = fmaf(s_woff[gk * 8 + c],     sv, dy);
            dx = fmaf(s_woff[gk * 8 + 4 + c], sv, dx);
        }
        float py = (float)(h + ky - 1) + dy;
        float px = (float)(w0 + wl + kx - 1) + dx;
        float y0 = floorf(py), x0 = floorf(px);
        float fy = py - y0, fx = px - x0;
        int iy = (int)y0, ix = (int)x0;
        bool y0v = (unsigned)iy       < (unsigned)Hn;
        bool y1v = (unsigned)(iy + 1) < (unsigned)Hn;
        bool x0v = (unsigned)ix       < (unsigned)Wn;
        bool x1v = (unsigned)(ix + 1) < (unsigned)Wn;
        int yc0 = min(max(iy, 0), Hn - 1), yc1 = min(max(iy + 1, 0), Hn - 1);
        int xc0 = min(max(ix, 0), Wn - 1), xc1 = min(max(ix + 1, 0), Wn - 1);
        int l00 = yc0 * Wn + xc0;
        int dx1 = xc1 - xc0, dy1 = yc1 - yc0;             // in {0,1}
        float wy1 = fy, wy0 = 1.f - fy, wx1 = fx, wx0 = 1.f - fx;
        float w00 = (y0v && x0v) ? wy0 * wx0 : 0.f;
        float w01 = (y0v && x1v) ? wy0 * wx1 : 0.f;
        float w10 = (y1v && x0v) ? wy1 * wx0 : 0.f;
        float w11 = (y1v && x1v) ? wy1 * wx1 : 0.f;
        f16x2 p0, p1;
        p0.x = (_Float16)w00; p0.y = (_Float16)w01;
        p1.x = (_Float16)w10; p1.y = (_Float16)w11;
        s_meta_a[i] = l00 | (dx1 << 12) | (dy1 << 13);
        s_meta_w[i] = make_int2(__builtin_bit_cast(int, p0),
                                __builtin_bit_cast(int, p1));
    }

    f16x8 c4a[4], c4b[4];
    int2  amva, amvb;
    const unsigned nBase = ((unsigned)(bp * 2 + (nl >> 5)) << 20) + (unsigned)cg * 8u;

    f32x4 acc[2][4];
#pragma unroll
    for (int mt = 0; mt < 2; mt++)
#pragma unroll
        for (int nt = 0; nt < 4; nt++) acc[mt][nt] = (f32x4){0.f, 0.f, 0.f, 0.f};

    __syncthreads();            // meta visible

    // prologue: sB[0] = {gk0, gk1}; c4a<-gk2, c4b<-gk3 in flight
    ISSUE(c4a, amva, 0);
    ISSUE(c4b, amvb, 1);
    COMMIT(c4a, amva, 0, 0);
    ISSUE(c4a, amva, 2);
    COMMIT(c4b, amvb, 0, 1);
    ISSUE(c4b, amvb, 3);
    __syncthreads();

    // 18 pair-iterations; ONE lgkm-only barrier each.
    for (int P = 0; P < GK / 2; P++) {
        const int rb = P & 1, wb = rb ^ 1;
        const int g0 = 2 * P;
        HALF(g0, rb, 0,
             if (g0 + 2 < GK) COMMIT(c4a, amva, wb, 0);
             if (g0 + 4 < GK) ISSUE(c4a, amva, g0 + 4); );
        HALF(g0 + 1, rb, 1,
             if (g0 + 3 < GK) COMMIT(c4b, amvb, wb, 1);
             if (g0 + 5 < GK) ISSUE(c4b, amvb, g0 + 5); );
        // lgkm-only barrier: commit ds_writes + bfv/meta ds_reads drained;
        // private global gathers (c4/af) stay in flight across it.
        asm volatile("s_waitcnt lgkmcnt(0)" ::: "memory");
        __builtin_amdgcn_s_barrier();
    }

    // ---- epilogue: o = wid*32 + mt*16 + quad*4 + r ; n = nt*16 + col ----
#pragma unroll
    for (int mt = 0; mt < 2; mt++)
#pragma unroll
        for (int r = 0; r < 4; r++) {
            int o = wid * 32 + mt * 16 + quad * 4 + r;
#pragma unroll
            for (int nt = 0; nt < 4; nt++) {
                int n = nt * 16 + col;
                int b = bp * 2 + (n >> 5);
                int w = w0 + (n & 31);
                out[(((size_t)(b * COUT + o)) << 12) + h * Wn + w] =
                    fmaxf(acc[mt][nt][r], 0.f);
            }
        }
}

// ---------------------------------------------------------------------------
extern "C" void kernel_launch(void* const* d_in, const int* in_sizes, int n_in,
                              void* d_out, int out_size, void* d_ws, size_t ws_size,
                              hipStream_t stream) {
    const float* x     = (const float*)d_in[0];
    const float* shp   = (const float*)d_in[1];
    const float* w_off = (const float*)d_in[2];
    const float* w_def = (const float*)d_in[3];
    float* out = (float*)d_out;
    _Float16* wfrag = (_Float16*)d_ws;                       // 1.18 MB
    _Float16* xt    = (_Float16*)((char*)d_ws + (2u << 20)); // 16.8 MB

    fa_prep<<<1024 + 32, 256, 0, stream>>>(x, w_def, xt, wfrag);
    fa_main<<<512, 512, 0, stream>>>(xt, shp, w_off, wfrag, out);
}